// Round 1
// baseline (37742.499 us; speedup 1.0000x reference)
//
#include <hip/hip_runtime.h>
#include <math.h>

#define N_NODES 20000
#define N_EDGES 320000
#define F_IN 128
#define C 300
#define L_STEPS 8
#define BK 16

// ---------------- pad x (N x 128) -> h (N x 300) ----------------
__global__ void pad_kernel(const float* __restrict__ x, float* __restrict__ h) {
    int idx = blockIdx.x * blockDim.x + threadIdx.x;
    if (idx >= N_NODES * C) return;
    int n = idx / C, c = idx - n * C;
    h[idx] = (c < F_IN) ? x[n * F_IN + c] : 0.0f;
}

// ---------------- fp32 tiled GEMM: Cout[M,N] = A[M,K] @ B[K,N] ----------------
// BM=64, BN=64, BK=16; 256 threads; 4x4 micro-tile.
__launch_bounds__(256)
__global__ void gemm_nn(const float* __restrict__ A, const float* __restrict__ B,
                        float* __restrict__ Cout, int M, int N, int K) {
    __shared__ float As[BK][68];   // [k][m], padded
    __shared__ float Bs[BK][68];   // [k][n], padded
    const int tid = threadIdx.x;
    const int tx = tid & 15, ty = tid >> 4;
    const int rowBase = blockIdx.y * 64;
    const int colBase = blockIdx.x * 64;
    float acc[4][4] = {};

    const int rowA = tid >> 2;          // 0..63
    const int k4   = (tid & 3) * 4;     // 0,4,8,12
    const int cB   = tid & 63;
    const int kB0  = tid >> 6;          // 0..3

    const int ktiles = (K + BK - 1) / BK;
    for (int kt = 0; kt < ktiles; ++kt) {
        const int k0 = kt * BK;
        // stage A: thread loads float4 along k for one row
        {
            int gr = rowBase + rowA;
            if (k0 + BK <= K) {
                float4 v = (gr < M) ? *(const float4*)&A[(size_t)gr * K + k0 + k4]
                                    : make_float4(0.f, 0.f, 0.f, 0.f);
                As[k4 + 0][rowA] = v.x; As[k4 + 1][rowA] = v.y;
                As[k4 + 2][rowA] = v.z; As[k4 + 3][rowA] = v.w;
            } else {
                #pragma unroll
                for (int j = 0; j < 4; ++j) {
                    int k = k0 + k4 + j;
                    As[k4 + j][rowA] = (gr < M && k < K) ? A[(size_t)gr * K + k] : 0.f;
                }
            }
        }
        // stage B: coalesced rows of B
        #pragma unroll
        for (int i = 0; i < 4; ++i) {
            int k = kB0 + i * 4;
            int gk = k0 + k, gc = colBase + cB;
            Bs[k][cB] = (gk < K && gc < N) ? B[(size_t)gk * N + gc] : 0.f;
        }
        __syncthreads();
        #pragma unroll
        for (int k = 0; k < BK; ++k) {
            float4 a = *(const float4*)&As[k][ty * 4];
            float4 b = *(const float4*)&Bs[k][tx * 4];
            float av[4] = {a.x, a.y, a.z, a.w};
            float bv[4] = {b.x, b.y, b.z, b.w};
            #pragma unroll
            for (int i = 0; i < 4; ++i)
                #pragma unroll
                for (int j = 0; j < 4; ++j)
                    acc[i][j] += av[i] * bv[j];
        }
        __syncthreads();
    }
    #pragma unroll
    for (int i = 0; i < 4; ++i) {
        int gr = rowBase + ty * 4 + i;
        if (gr >= M) continue;
        #pragma unroll
        for (int j = 0; j < 4; ++j) {
            int gc = colBase + tx * 4 + j;
            if (gc < N) Cout[(size_t)gr * N + gc] = acc[i][j];
        }
    }
}

// ---------------- scatter-add: agg[dst[e],:] += m[src[e],:] ----------------
__global__ void scatter_kernel(const float* __restrict__ m, const int* __restrict__ src,
                               const int* __restrict__ dst, float* __restrict__ agg) {
    const int Q = C / 4;  // 75 float4 per row
    int idx = blockIdx.x * blockDim.x + threadIdx.x;
    if (idx >= N_EDGES * Q) return;
    int e = idx / Q;
    int q = idx - e * Q;
    int s = src[e], d = dst[e];
    float4 v = *(const float4*)&m[(size_t)s * C + q * 4];
    float* a = &agg[(size_t)d * C + q * 4];
    atomicAdd(a + 0, v.x);
    atomicAdd(a + 1, v.y);
    atomicAdd(a + 2, v.z);
    atomicAdd(a + 3, v.w);
}

// ---------------- fused GRU: hout = GRUCell(agg, h) ----------------
// Computes 6 GEMM tiles (agg@wih^T r/z/n, h@whh^T r/z/n) + gates, fused.
// BM=64 rows, BN=32 gate-cols, BK=16.
__launch_bounds__(256)
__global__ void gru_fused(const float* __restrict__ agg, const float* __restrict__ h,
                          const float* __restrict__ wih, const float* __restrict__ whh,
                          const float* __restrict__ bih, const float* __restrict__ bhh,
                          float* __restrict__ hout) {
    __shared__ float Aag[BK][68];       // [k][m]
    __shared__ float Ah [BK][68];
    __shared__ float Bsh[6][BK][36];    // [tile][k][c]; tiles 0..2 = wih r/z/n, 3..5 = whh r/z/n
    const int tid = threadIdx.x;
    const int tx = tid & 15;   // cols: c = tx*2 + j
    const int ty = tid >> 4;   // rows: r = ty*4 + i
    const int rowBase = blockIdx.y * 64;
    const int colBase = blockIdx.x * 32;
    float acc[6][4][2] = {};

    const int rowA = tid >> 2;
    const int k4   = (tid & 3) * 4;

    const int ktiles = (C + BK - 1) / BK;  // 19
    for (int kt = 0; kt < ktiles; ++kt) {
        const int k0 = kt * BK;
        // stage A (both matrices)
        {
            int gr = rowBase + rowA;
            if (k0 + BK <= C) {
                float4 va = (gr < N_NODES) ? *(const float4*)&agg[(size_t)gr * C + k0 + k4]
                                           : make_float4(0.f, 0.f, 0.f, 0.f);
                float4 vh = (gr < N_NODES) ? *(const float4*)&h[(size_t)gr * C + k0 + k4]
                                           : make_float4(0.f, 0.f, 0.f, 0.f);
                Aag[k4 + 0][rowA] = va.x; Aag[k4 + 1][rowA] = va.y;
                Aag[k4 + 2][rowA] = va.z; Aag[k4 + 3][rowA] = va.w;
                Ah [k4 + 0][rowA] = vh.x; Ah [k4 + 1][rowA] = vh.y;
                Ah [k4 + 2][rowA] = vh.z; Ah [k4 + 3][rowA] = vh.w;
            } else {
                #pragma unroll
                for (int j = 0; j < 4; ++j) {
                    int k = k0 + k4 + j;
                    bool ok = (gr < N_NODES) && (k < C);
                    Aag[k4 + j][rowA] = ok ? agg[(size_t)gr * C + k] : 0.f;
                    Ah [k4 + j][rowA] = ok ? h[(size_t)gr * C + k] : 0.f;
                }
            }
        }
        // stage B: 6 tiles x 32 rows x 16 k = 768 float4 slots; 3 per thread
        #pragma unroll
        for (int i = 0; i < 3; ++i) {
            int f = tid + i * 256;          // 0..767
            int tile = f >> 7;              // 0..5
            int rr = (f >> 2) & 31;         // row in tile
            int kq = (f & 3) * 4;
            const float* Wm = (tile < 3) ? wih : whh;
            int g = (tile < 3) ? tile : tile - 3;
            int c = colBase + rr;
            if (c < C && k0 + BK <= C) {
                float4 v = *(const float4*)&Wm[(size_t)(g * C + c) * C + k0 + kq];
                Bsh[tile][kq + 0][rr] = v.x; Bsh[tile][kq + 1][rr] = v.y;
                Bsh[tile][kq + 2][rr] = v.z; Bsh[tile][kq + 3][rr] = v.w;
            } else {
                #pragma unroll
                for (int j = 0; j < 4; ++j) {
                    int k = k0 + kq + j;
                    Bsh[tile][kq + j][rr] = (c < C && k < C) ? Wm[(size_t)(g * C + c) * C + k] : 0.f;
                }
            }
        }
        __syncthreads();
        #pragma unroll
        for (int k = 0; k < BK; ++k) {
            float4 aa = *(const float4*)&Aag[k][ty * 4];
            float4 ah = *(const float4*)&Ah[k][ty * 4];
            float av[4] = {aa.x, aa.y, aa.z, aa.w};
            float hv[4] = {ah.x, ah.y, ah.z, ah.w};
            float2 b0 = *(const float2*)&Bsh[0][k][tx * 2];
            float2 b1 = *(const float2*)&Bsh[1][k][tx * 2];
            float2 b2 = *(const float2*)&Bsh[2][k][tx * 2];
            float2 b3 = *(const float2*)&Bsh[3][k][tx * 2];
            float2 b4 = *(const float2*)&Bsh[4][k][tx * 2];
            float2 b5 = *(const float2*)&Bsh[5][k][tx * 2];
            float bi[6][2] = {{b0.x, b0.y}, {b1.x, b1.y}, {b2.x, b2.y},
                              {b3.x, b3.y}, {b4.x, b4.y}, {b5.x, b5.y}};
            #pragma unroll
            for (int i = 0; i < 4; ++i) {
                #pragma unroll
                for (int j = 0; j < 2; ++j) {
                    acc[0][i][j] += av[i] * bi[0][j];
                    acc[1][i][j] += av[i] * bi[1][j];
                    acc[2][i][j] += av[i] * bi[2][j];
                    acc[3][i][j] += hv[i] * bi[3][j];
                    acc[4][i][j] += hv[i] * bi[4][j];
                    acc[5][i][j] += hv[i] * bi[5][j];
                }
            }
        }
        __syncthreads();
    }
    // epilogue: gates
    #pragma unroll
    for (int i = 0; i < 4; ++i) {
        int gr = rowBase + ty * 4 + i;
        if (gr >= N_NODES) continue;
        #pragma unroll
        for (int j = 0; j < 2; ++j) {
            int c = colBase + tx * 2 + j;
            if (c >= C) continue;
            float ir = acc[0][i][j] + bih[c];
            float iz = acc[1][i][j] + bih[C + c];
            float in_ = acc[2][i][j] + bih[2 * C + c];
            float hr = acc[3][i][j] + bhh[c];
            float hz = acc[4][i][j] + bhh[C + c];
            float hn = acc[5][i][j] + bhh[2 * C + c];
            float r = 1.f / (1.f + __expf(-(ir + hr)));
            float z = 1.f / (1.f + __expf(-(iz + hz)));
            float nn = tanhf(in_ + r * hn);
            float hold = h[(size_t)gr * C + c];
            hout[(size_t)gr * C + c] = (1.f - z) * nn + z * hold;
        }
    }
}

// ---------------- relu in place ----------------
__global__ void relu_kernel(float* __restrict__ h) {
    int idx = blockIdx.x * blockDim.x + threadIdx.x;
    if (idx < N_NODES * C) h[idx] = fmaxf(h[idx], 0.f);
}

// ---------------- mean pool (partial sums + atomics) ----------------
__global__ void pool_kernel(const float* __restrict__ h, float* __restrict__ pooled) {
    int c = threadIdx.x;
    if (c >= C) return;
    float acc = 0.f;
    for (int n = blockIdx.x; n < N_NODES; n += gridDim.x)
        acc += h[(size_t)n * C + c];
    atomicAdd(&pooled[c], acc);
}

// ---------------- log_softmax of pooled/N ----------------
__global__ void lsm_kernel(const float* __restrict__ pooled, float* __restrict__ out) {
    __shared__ float sm[512];
    int t = threadIdx.x;
    float v = (t < C) ? pooled[t] * (1.0f / N_NODES) : -INFINITY;
    sm[t] = v;
    __syncthreads();
    for (int s = 256; s > 0; s >>= 1) {
        if (t < s) sm[t] = fmaxf(sm[t], sm[t + s]);
        __syncthreads();
    }
    float mx = sm[0];
    __syncthreads();
    float e = (t < C) ? expf(v - mx) : 0.f;
    sm[t] = e;
    __syncthreads();
    for (int s = 256; s > 0; s >>= 1) {
        if (t < s) sm[t] += sm[t + s];
        __syncthreads();
    }
    float lse = logf(sm[0]);
    if (t < C) out[t] = (v - mx) - lse;
}

extern "C" void kernel_launch(void* const* d_in, const int* in_sizes, int n_in,
                              void* d_out, int out_size, void* d_ws, size_t ws_size,
                              hipStream_t stream) {
    const float* x      = (const float*)d_in[0];
    const int*   ei     = (const int*)d_in[1];
    const int*   src    = ei;
    const int*   dst    = ei + N_EDGES;
    const float* W1     = (const float*)d_in[2];
    const float* g1_wih = (const float*)d_in[3];
    const float* g1_whh = (const float*)d_in[4];
    const float* g1_bih = (const float*)d_in[5];
    const float* g1_bhh = (const float*)d_in[6];
    const float* W2     = (const float*)d_in[7];
    const float* g2_wih = (const float*)d_in[8];
    const float* g2_whh = (const float*)d_in[9];
    const float* g2_bih = (const float*)d_in[10];
    const float* g2_bhh = (const float*)d_in[11];

    const size_t NC = (size_t)N_NODES * C;
    float* bufA   = (float*)d_ws;
    float* bufB   = bufA + NC;
    float* bufG   = bufB + NC;
    float* pooled = bufG + NC;

    pad_kernel<<<(N_NODES * C + 255) / 256, 256, 0, stream>>>(x, bufA);

    float* h  = bufA;
    float* mb = bufB;
    const int gridY = (N_NODES + 63) / 64;  // 313

    for (int layer = 0; layer < 2; ++layer) {
        const float* W   = layer ? W2 : W1;
        const float* wih = layer ? g2_wih : g1_wih;
        const float* whh = layer ? g2_whh : g1_whh;
        const float* bih = layer ? g2_bih : g1_bih;
        const float* bhh = layer ? g2_bhh : g1_bhh;
        for (int step = 0; step < L_STEPS; ++step) {
            gemm_nn<<<dim3((C + 63) / 64, gridY), 256, 0, stream>>>(
                h, W + (size_t)step * C * C, mb, N_NODES, C, C);
            hipMemsetAsync(bufG, 0, NC * sizeof(float), stream);
            scatter_kernel<<<(N_EDGES * (C / 4) + 255) / 256, 256, 0, stream>>>(
                mb, src, dst, bufG);
            gru_fused<<<dim3((C + 31) / 32, gridY), 256, 0, stream>>>(
                bufG, h, wih, whh, bih, bhh, mb);
            float* tmp = h; h = mb; mb = tmp;
        }
        if (layer == 0)
            relu_kernel<<<(N_NODES * C + 255) / 256, 256, 0, stream>>>(h);
    }

    hipMemsetAsync(pooled, 0, C * sizeof(float), stream);
    pool_kernel<<<256, 320, 0, stream>>>(h, pooled);
    lsm_kernel<<<1, 512, 0, stream>>>(pooled, (float*)d_out);
}

// Round 4
// 15971.135 us; speedup vs baseline: 2.3632x; 2.3632x over previous
//
#include <hip/hip_runtime.h>
#include <math.h>

#define N_NODES 20000
#define N_EDGES 320000
#define F_IN 128
#define C 300
#define L_STEPS 8
#define BK 16

// ---------------- pad x (N x 128) -> h (N x 300) ----------------
__global__ void pad_kernel(const float* __restrict__ x, float* __restrict__ h) {
    int idx = blockIdx.x * blockDim.x + threadIdx.x;
    if (idx >= N_NODES * C) return;
    int n = idx / C, c = idx - n * C;
    h[idx] = (c < F_IN) ? x[n * F_IN + c] : 0.0f;
}

// ---------------- CSR build ----------------
__global__ void hist_kernel(const int* __restrict__ dst, int* __restrict__ deg) {
    int e = blockIdx.x * blockDim.x + threadIdx.x;
    if (e < N_EDGES) atomicAdd(&deg[dst[e]], 1);
}

__global__ void scan_kernel(const int* __restrict__ deg, int* __restrict__ row_ptr) {
    __shared__ int part[1024];
    const int PER = 20;   // 1024*20 >= 20000
    int t = threadIdx.x;
    int base = t * PER;
    int vals[PER];
    int s = 0;
    #pragma unroll
    for (int i = 0; i < PER; ++i) {
        int idx = base + i;
        int v = (idx < N_NODES) ? deg[idx] : 0;
        vals[i] = s; s += v;
    }
    part[t] = s;
    __syncthreads();
    for (int off = 1; off < 1024; off <<= 1) {
        int v = (t >= off) ? part[t - off] : 0;
        __syncthreads();
        part[t] += v;
        __syncthreads();
    }
    int pre = (t == 0) ? 0 : part[t - 1];
    #pragma unroll
    for (int i = 0; i < PER; ++i) {
        int idx = base + i;
        if (idx < N_NODES) row_ptr[idx] = pre + vals[i];
    }
    if (t == 0) row_ptr[N_NODES] = N_EDGES;
}

__global__ void cursor_copy(const int* __restrict__ row_ptr, int* __restrict__ cur) {
    int i = blockIdx.x * blockDim.x + threadIdx.x;
    if (i < N_NODES) cur[i] = row_ptr[i];
}

__global__ void fill_kernel(const int* __restrict__ src, const int* __restrict__ dst,
                            int* __restrict__ cur, int* __restrict__ colx) {
    int e = blockIdx.x * blockDim.x + threadIdx.x;
    if (e >= N_EDGES) return;
    int d = dst[e];
    int p = atomicAdd(&cur[d], 1);
    colx[p] = src[e];
}

// ---------------- wcombT[gn][r] = sum_j W[r][j] * wih[gn][j]  (fp32) -------
// Contract-over-last-index GEMM (both inputs row-major over the contraction).
__launch_bounds__(256)
__global__ void wcombT_kernel(const float* __restrict__ W,     // [C][C], one step
                              const float* __restrict__ wih,   // [3C][C]
                              float* __restrict__ out) {       // [3C][C]
    __shared__ float As[BK][68];
    __shared__ float Bs[BK][68];
    int tid = threadIdx.x;
    int tx = tid & 15, ty = tid >> 4;
    int rowBase = blockIdx.y * 64, colBase = blockIdx.x * 64;
    float acc[4][4] = {};
    int lr = tid >> 2, k4 = (tid & 3) * 4;
    for (int k0 = 0; k0 < C; k0 += BK) {
        {
            int gr = rowBase + lr;      // r index into W
            int gn = colBase + lr;      // gn index into wih
            #pragma unroll
            for (int j = 0; j < 4; ++j) {
                int k = k0 + k4 + j;
                As[k4 + j][lr] = (gr < C && k < C) ? W[(size_t)gr * C + k] : 0.f;
                Bs[k4 + j][lr] = (gn < 3 * C && k < C) ? wih[(size_t)gn * C + k] : 0.f;
            }
        }
        __syncthreads();
        #pragma unroll
        for (int k = 0; k < BK; ++k) {
            float4 a = *(const float4*)&As[k][ty * 4];
            float4 b = *(const float4*)&Bs[k][tx * 4];
            float av[4] = {a.x, a.y, a.z, a.w};
            float bv[4] = {b.x, b.y, b.z, b.w};
            #pragma unroll
            for (int i = 0; i < 4; ++i)
                #pragma unroll
                for (int j = 0; j < 4; ++j)
                    acc[i][j] += av[i] * bv[j];
        }
        __syncthreads();
    }
    #pragma unroll
    for (int i = 0; i < 4; ++i) {
        int r = rowBase + ty * 4 + i;
        if (r >= C) continue;
        #pragma unroll
        for (int j = 0; j < 4; ++j) {
            int gn = colBase + tx * 4 + j;
            if (gn < 3 * C) out[(size_t)gn * C + r] = acc[i][j];
        }
    }
}

// ---------------- CSR gather (fp32): agg[n][:] = sum_{e: dst=n} h[src[e]][:] ----
__global__ void aggregate_kernel(const float* __restrict__ h,
                                 const int* __restrict__ rowp,
                                 const int* __restrict__ colx,
                                 float* __restrict__ agg) {
    const int node = blockIdx.x * 4 + (threadIdx.x >> 6);
    const int lane = threadIdx.x & 63;
    const int beg = rowp[node], end = rowp[node + 1];
    float4 a0 = make_float4(0.f, 0.f, 0.f, 0.f);
    float4 a1 = make_float4(0.f, 0.f, 0.f, 0.f);
    const bool tail = lane < 11;       // chunks 64..74 cover cols 256..299
    for (int e = beg; e < end; ++e) {
        const float* row = h + (size_t)colx[e] * C;
        float4 v = *(const float4*)&row[lane * 4];
        a0.x += v.x; a0.y += v.y; a0.z += v.z; a0.w += v.w;
        if (tail) {
            float4 u = *(const float4*)&row[(64 + lane) * 4];
            a1.x += u.x; a1.y += u.y; a1.z += u.z; a1.w += u.w;
        }
    }
    float* orow = agg + (size_t)node * C;
    *(float4*)&orow[lane * 4] = a0;
    if (tail) *(float4*)&orow[(64 + lane) * 4] = a1;
}

// ---------------- fused GRU (round-1 verified): hout = GRUCell(agg, h) -----
// BM=64 rows, BN=32 gate-cols, BK=16; wih here is wcombT [3C][C].
__launch_bounds__(256)
__global__ void gru_fused(const float* __restrict__ agg, const float* __restrict__ h,
                          const float* __restrict__ wih, const float* __restrict__ whh,
                          const float* __restrict__ bih, const float* __restrict__ bhh,
                          float* __restrict__ hout) {
    __shared__ float Aag[BK][68];       // [k][m]
    __shared__ float Ah [BK][68];
    __shared__ float Bsh[6][BK][36];    // [tile][k][c]; tiles 0..2 = wih r/z/n, 3..5 = whh r/z/n
    const int tid = threadIdx.x;
    const int tx = tid & 15;   // cols: c = tx*2 + j
    const int ty = tid >> 4;   // rows: r = ty*4 + i
    const int rowBase = blockIdx.y * 64;
    const int colBase = blockIdx.x * 32;
    float acc[6][4][2] = {};

    const int rowA = tid >> 2;
    const int k4   = (tid & 3) * 4;

    const int ktiles = (C + BK - 1) / BK;  // 19
    for (int kt = 0; kt < ktiles; ++kt) {
        const int k0 = kt * BK;
        // stage A (both matrices)
        {
            int gr = rowBase + rowA;
            if (k0 + BK <= C) {
                float4 va = (gr < N_NODES) ? *(const float4*)&agg[(size_t)gr * C + k0 + k4]
                                           : make_float4(0.f, 0.f, 0.f, 0.f);
                float4 vh = (gr < N_NODES) ? *(const float4*)&h[(size_t)gr * C + k0 + k4]
                                           : make_float4(0.f, 0.f, 0.f, 0.f);
                Aag[k4 + 0][rowA] = va.x; Aag[k4 + 1][rowA] = va.y;
                Aag[k4 + 2][rowA] = va.z; Aag[k4 + 3][rowA] = va.w;
                Ah [k4 + 0][rowA] = vh.x; Ah [k4 + 1][rowA] = vh.y;
                Ah [k4 + 2][rowA] = vh.z; Ah [k4 + 3][rowA] = vh.w;
            } else {
                #pragma unroll
                for (int j = 0; j < 4; ++j) {
                    int k = k0 + k4 + j;
                    bool ok = (gr < N_NODES) && (k < C);
                    Aag[k4 + j][rowA] = ok ? agg[(size_t)gr * C + k] : 0.f;
                    Ah [k4 + j][rowA] = ok ? h[(size_t)gr * C + k] : 0.f;
                }
            }
        }
        // stage B: 6 tiles x 32 rows x 16 k = 768 float4 slots; 3 per thread
        #pragma unroll
        for (int i = 0; i < 3; ++i) {
            int f = tid + i * 256;          // 0..767
            int tile = f >> 7;              // 0..5
            int rr = (f >> 2) & 31;         // row in tile
            int kq = (f & 3) * 4;
            const float* Wm = (tile < 3) ? wih : whh;
            int g = (tile < 3) ? tile : tile - 3;
            int c = colBase + rr;
            if (c < C && k0 + BK <= C) {
                float4 v = *(const float4*)&Wm[(size_t)(g * C + c) * C + k0 + kq];
                Bsh[tile][kq + 0][rr] = v.x; Bsh[tile][kq + 1][rr] = v.y;
                Bsh[tile][kq + 2][rr] = v.z; Bsh[tile][kq + 3][rr] = v.w;
            } else {
                #pragma unroll
                for (int j = 0; j < 4; ++j) {
                    int k = k0 + kq + j;
                    Bsh[tile][kq + j][rr] = (c < C && k < C) ? Wm[(size_t)(g * C + c) * C + k] : 0.f;
                }
            }
        }
        __syncthreads();
        #pragma unroll
        for (int k = 0; k < BK; ++k) {
            float4 aa = *(const float4*)&Aag[k][ty * 4];
            float4 ah = *(const float4*)&Ah[k][ty * 4];
            float av[4] = {aa.x, aa.y, aa.z, aa.w};
            float hv[4] = {ah.x, ah.y, ah.z, ah.w};
            float2 b0 = *(const float2*)&Bsh[0][k][tx * 2];
            float2 b1 = *(const float2*)&Bsh[1][k][tx * 2];
            float2 b2 = *(const float2*)&Bsh[2][k][tx * 2];
            float2 b3 = *(const float2*)&Bsh[3][k][tx * 2];
            float2 b4 = *(const float2*)&Bsh[4][k][tx * 2];
            float2 b5 = *(const float2*)&Bsh[5][k][tx * 2];
            float bi[6][2] = {{b0.x, b0.y}, {b1.x, b1.y}, {b2.x, b2.y},
                              {b3.x, b3.y}, {b4.x, b4.y}, {b5.x, b5.y}};
            #pragma unroll
            for (int i = 0; i < 4; ++i) {
                #pragma unroll
                for (int j = 0; j < 2; ++j) {
                    acc[0][i][j] += av[i] * bi[0][j];
                    acc[1][i][j] += av[i] * bi[1][j];
                    acc[2][i][j] += av[i] * bi[2][j];
                    acc[3][i][j] += hv[i] * bi[3][j];
                    acc[4][i][j] += hv[i] * bi[4][j];
                    acc[5][i][j] += hv[i] * bi[5][j];
                }
            }
        }
        __syncthreads();
    }
    // epilogue: gates
    #pragma unroll
    for (int i = 0; i < 4; ++i) {
        int gr = rowBase + ty * 4 + i;
        if (gr >= N_NODES) continue;
        #pragma unroll
        for (int j = 0; j < 2; ++j) {
            int c = colBase + tx * 2 + j;
            if (c >= C) continue;
            float ir = acc[0][i][j] + bih[c];
            float iz = acc[1][i][j] + bih[C + c];
            float in_ = acc[2][i][j] + bih[2 * C + c];
            float hr = acc[3][i][j] + bhh[c];
            float hz = acc[4][i][j] + bhh[C + c];
            float hn = acc[5][i][j] + bhh[2 * C + c];
            float r = 1.f / (1.f + __expf(-(ir + hr)));
            float z = 1.f / (1.f + __expf(-(iz + hz)));
            float nn = tanhf(in_ + r * hn);
            float hold = h[(size_t)gr * C + c];
            hout[(size_t)gr * C + c] = (1.f - z) * nn + z * hold;
        }
    }
}

// ---------------- relu in place ----------------
__global__ void relu_kernel(float* __restrict__ h) {
    int idx = blockIdx.x * blockDim.x + threadIdx.x;
    if (idx < N_NODES * C) h[idx] = fmaxf(h[idx], 0.f);
}

// ---------------- mean pool ----------------
__global__ void pool_kernel(const float* __restrict__ h, float* __restrict__ pooled) {
    int c = threadIdx.x;
    if (c >= C) return;
    float acc = 0.f;
    for (int n = blockIdx.x; n < N_NODES; n += gridDim.x)
        acc += h[(size_t)n * C + c];
    atomicAdd(&pooled[c], acc);
}

// ---------------- log_softmax ----------------
__global__ void lsm_kernel(const float* __restrict__ pooled, float* __restrict__ out) {
    __shared__ float sm[512];
    int t = threadIdx.x;
    float v = (t < C) ? pooled[t] * (1.0f / N_NODES) : -INFINITY;
    sm[t] = v;
    __syncthreads();
    for (int s = 256; s > 0; s >>= 1) {
        if (t < s) sm[t] = fmaxf(sm[t], sm[t + s]);
        __syncthreads();
    }
    float mx = sm[0];
    __syncthreads();
    float e = (t < C) ? expf(v - mx) : 0.f;
    sm[t] = e;
    __syncthreads();
    for (int s = 256; s > 0; s >>= 1) {
        if (t < s) sm[t] += sm[t + s];
        __syncthreads();
    }
    float lse = logf(sm[0]);
    if (t < C) out[t] = (v - mx) - lse;
}

extern "C" void kernel_launch(void* const* d_in, const int* in_sizes, int n_in,
                              void* d_out, int out_size, void* d_ws, size_t ws_size,
                              hipStream_t stream) {
    const float* x      = (const float*)d_in[0];
    const int*   ei     = (const int*)d_in[1];
    const int*   src    = ei;
    const int*   dst    = ei + N_EDGES;
    const float* W1     = (const float*)d_in[2];
    const float* g1_wih = (const float*)d_in[3];
    const float* g1_whh = (const float*)d_in[4];
    const float* g1_bih = (const float*)d_in[5];
    const float* g1_bhh = (const float*)d_in[6];
    const float* W2     = (const float*)d_in[7];
    const float* g2_wih = (const float*)d_in[8];
    const float* g2_whh = (const float*)d_in[9];
    const float* g2_bih = (const float*)d_in[10];
    const float* g2_bhh = (const float*)d_in[11];

    const size_t NC = (size_t)N_NODES * C;
    char* p = (char*)d_ws;
    float* P0 = (float*)p;      p += NC * 4;                 // 24,000,000
    float* P1 = (float*)p;      p += NC * 4;                 // 24,000,000  (agg)
    float* P2 = (float*)p;      p += NC * 4;                 // 24,000,000
    float* wct = (float*)p;     p += (size_t)3 * C * C * 4;  //  1,080,000
    int* row_ptr = (int*)p;     p += 80016;
    int* colx = (int*)p;        p += (size_t)N_EDGES * 4;    //  1,280,000
    float* pooled = (float*)p;  p += 1216;
    // deg/cursor overlay the wct region (dead before first wcombT_kernel)
    int* deg = (int*)wct;
    int* cursor = (int*)wct + N_NODES;

    hipMemsetAsync(deg, 0, N_NODES * sizeof(int), stream);
    hipMemsetAsync(pooled, 0, C * sizeof(float), stream);

    pad_kernel<<<(N_NODES * C + 255) / 256, 256, 0, stream>>>(x, P0);

    hist_kernel<<<(N_EDGES + 255) / 256, 256, 0, stream>>>(dst, deg);
    scan_kernel<<<1, 1024, 0, stream>>>(deg, row_ptr);
    cursor_copy<<<(N_NODES + 255) / 256, 256, 0, stream>>>(row_ptr, cursor);
    fill_kernel<<<(N_EDGES + 255) / 256, 256, 0, stream>>>(src, dst, cursor, colx);

    float* h  = P0;
    float* ag = P1;
    float* ho = P2;
    const int gridY = (N_NODES + 63) / 64;  // 313

    for (int layer = 0; layer < 2; ++layer) {
        const float* W   = layer ? W2 : W1;
        const float* wih = layer ? g2_wih : g1_wih;
        const float* whh = layer ? g2_whh : g1_whh;
        const float* bih = layer ? g2_bih : g1_bih;
        const float* bhh = layer ? g2_bhh : g1_bhh;
        for (int step = 0; step < L_STEPS; ++step) {
            wcombT_kernel<<<dim3(15, 5), 256, 0, stream>>>(
                W + (size_t)step * C * C, wih, wct);
            aggregate_kernel<<<N_NODES / 4, 256, 0, stream>>>(h, row_ptr, colx, ag);
            gru_fused<<<dim3((C + 31) / 32, gridY), 256, 0, stream>>>(
                ag, h, wct, whh, bih, bhh, ho);
            float* tmp = h; h = ho; ho = tmp;
        }
        if (layer == 0)
            relu_kernel<<<(N_NODES * C + 255) / 256, 256, 0, stream>>>(h);
    }

    pool_kernel<<<256, 320, 0, stream>>>(h, pooled);
    lsm_kernel<<<1, 512, 0, stream>>>(pooled, (float*)d_out);
}

// Round 6
// 11247.935 us; speedup vs baseline: 3.3555x; 1.4199x over previous
//
#include <hip/hip_runtime.h>
#include <math.h>

#define N_NODES 20000
#define N_EDGES 320000
#define F_IN 128
#define C 300
#define L_STEPS 8
#define KP 320                 // padded K (multiple of 32)
#define SP 328                 // LDS row stride (fp16 elems); 656 B/row, 16B-aligned, rotates banks
#define NPAD 304               // padded gate-col dim (19*16)
#define GOFS 97280             // 40*NPAD*8, per-gate block in swizzled weights
#define WSTEP 291840           // 3*GOFS, per (layer,step)
#define LOSCALE 2048.0f        // lo-part pre-scale (2^11), avoids fp16 denormals

typedef _Float16 half8 __attribute__((ext_vector_type(8)));
typedef _Float16 half4 __attribute__((ext_vector_type(4)));
typedef __attribute__((ext_vector_type(4))) float floatx4;

__device__ __forceinline__ void split16(float x, _Float16& hi, _Float16& lo) {
    hi = (_Float16)x;
    lo = (_Float16)((x - (float)hi) * LOSCALE);
}

// ---------------- pad x -> h (fp32) + hh/hl (fp16 split, stride KP) --------
__global__ void pad_kernel(const float* __restrict__ x, float* __restrict__ h,
                           _Float16* __restrict__ hh, _Float16* __restrict__ hl) {
    int idx = blockIdx.x * blockDim.x + threadIdx.x;
    if (idx >= N_NODES * KP) return;
    int n = idx / KP, c = idx - n * KP;
    float v = (c < F_IN) ? x[n * F_IN + c] : 0.0f;
    if (c < C) h[(size_t)n * C + c] = v;
    _Float16 hi, lo; split16(v, hi, lo);
    hh[idx] = hi; hl[idx] = lo;
}

// ---------------- CSR build (verified round 4) ----------------
__global__ void hist_kernel(const int* __restrict__ dst, int* __restrict__ deg) {
    int e = blockIdx.x * blockDim.x + threadIdx.x;
    if (e < N_EDGES) atomicAdd(&deg[dst[e]], 1);
}

__global__ void scan_kernel(const int* __restrict__ deg, int* __restrict__ row_ptr) {
    __shared__ int part[1024];
    const int PER = 20;
    int t = threadIdx.x;
    int base = t * PER;
    int vals[PER];
    int s = 0;
    #pragma unroll
    for (int i = 0; i < PER; ++i) {
        int idx = base + i;
        int v = (idx < N_NODES) ? deg[idx] : 0;
        vals[i] = s; s += v;
    }
    part[t] = s;
    __syncthreads();
    for (int off = 1; off < 1024; off <<= 1) {
        int v = (t >= off) ? part[t - off] : 0;
        __syncthreads();
        part[t] += v;
        __syncthreads();
    }
    int pre = (t == 0) ? 0 : part[t - 1];
    #pragma unroll
    for (int i = 0; i < PER; ++i) {
        int idx = base + i;
        if (idx < N_NODES) row_ptr[idx] = pre + vals[i];
    }
    if (t == 0) row_ptr[N_NODES] = N_EDGES;
}

__global__ void cursor_copy(const int* __restrict__ row_ptr, int* __restrict__ cur) {
    int i = blockIdx.x * blockDim.x + threadIdx.x;
    if (i < N_NODES) cur[i] = row_ptr[i];
}

__global__ void fill_kernel(const int* __restrict__ src, const int* __restrict__ dst,
                            int* __restrict__ cur, int* __restrict__ colx) {
    int e = blockIdx.x * blockDim.x + threadIdx.x;
    if (e >= N_EDGES) return;
    int d = dst[e];
    int p = atomicAdd(&cur[d], 1);
    colx[p] = src[e];
}

// ---- WcombT[r][gn] = sum_c W[r][c]*wih[gn][c]; swizzled fp16 hi/lo --------
// GEMM body identical to verified round-4 wcombT_kernel; only the store differs.
__launch_bounds__(256)
__global__ void wcomb_split(const float* __restrict__ W1, const float* __restrict__ W2,
                            const float* __restrict__ wih1, const float* __restrict__ wih2,
                            _Float16* __restrict__ whi, _Float16* __restrict__ wlo) {
    int z = blockIdx.z, layer = z >> 3, step = z & 7;
    const float* A  = (layer ? W2 : W1) + (size_t)step * C * C;  // [r][c]
    const float* Bm = layer ? wih2 : wih1;                       // [gn][c]
    _Float16* ohi = whi + (size_t)z * WSTEP;
    _Float16* olo = wlo + (size_t)z * WSTEP;
    __shared__ float As[16][68];
    __shared__ float Bs[16][68];
    int tid = threadIdx.x;
    int tx = tid & 15, ty = tid >> 4;
    int rowBase = blockIdx.y * 64, colBase = blockIdx.x * 64;
    float acc[4][4] = {};
    int lr = tid >> 2, k4 = (tid & 3) * 4;
    for (int k0 = 0; k0 < C; k0 += 16) {
        {
            int gr = rowBase + lr;
            int gn = colBase + lr;
            #pragma unroll
            for (int j = 0; j < 4; ++j) {
                int k = k0 + k4 + j;
                As[k4 + j][lr] = (gr < C && k < C) ? A[(size_t)gr * C + k] : 0.f;
                Bs[k4 + j][lr] = (gn < 3 * C && k < C) ? Bm[(size_t)gn * C + k] : 0.f;
            }
        }
        __syncthreads();
        #pragma unroll
        for (int k = 0; k < 16; ++k) {
            float4 a = *(const float4*)&As[k][ty * 4];
            float4 b = *(const float4*)&Bs[k][tx * 4];
            float av[4] = {a.x, a.y, a.z, a.w};
            float bv[4] = {b.x, b.y, b.z, b.w};
            #pragma unroll
            for (int i = 0; i < 4; ++i)
                #pragma unroll
                for (int j = 0; j < 4; ++j)
                    acc[i][j] += av[i] * bv[j];
        }
        __syncthreads();
    }
    #pragma unroll
    for (int i = 0; i < 4; ++i) {
        int r = rowBase + ty * 4 + i;
        if (r >= C) continue;
        #pragma unroll
        for (int j = 0; j < 4; ++j) {
            int gn = colBase + tx * 4 + j;
            if (gn >= 3 * C) continue;
            int g = (gn >= 2 * C) ? 2 : ((gn >= C) ? 1 : 0);
            int n = gn - g * C;
            size_t idx = (((size_t)g * 40 + (r >> 3)) * NPAD + n) * 8 + (r & 7);
            _Float16 hi, lo; split16(acc[i][j], hi, lo);
            ohi[idx] = hi; olo[idx] = lo;
        }
    }
}

// ---- whh^T swizzle + split: B[k][gn] = whh[gn][k], fp16 hi/lo ----
__global__ void whh_split(const float* __restrict__ whh1, const float* __restrict__ whh2,
                          _Float16* __restrict__ whi, _Float16* __restrict__ wlo) {
    int idx = blockIdx.x * blockDim.x + threadIdx.x;
    if (idx >= 2 * 3 * C * C) return;
    int k = idx % C;
    int rest = idx / C;
    int gn = rest % (3 * C);
    int layer = rest / (3 * C);
    int g = (gn >= 2 * C) ? 2 : ((gn >= C) ? 1 : 0);
    int n = gn - g * C;
    float v = (layer ? whh2 : whh1)[(size_t)gn * C + k];
    size_t o = (size_t)layer * WSTEP + (((size_t)g * 40 + (k >> 3)) * NPAD + n) * 8 + (k & 7);
    _Float16 hi, lo; split16(v, hi, lo);
    whi[o] = hi; wlo[o] = lo;
}

// ---- CSR gather from fp32 h -> exact fp16 hi/lo split agg [N x KP] ----
__global__ void aggregate_kernel(const float* __restrict__ h,
                                 const int* __restrict__ rowp,
                                 const int* __restrict__ colx,
                                 _Float16* __restrict__ agh, _Float16* __restrict__ agl) {
    const int node = blockIdx.x * 4 + (threadIdx.x >> 6);
    const int lane = threadIdx.x & 63;
    const int beg = rowp[node], end = rowp[node + 1];
    float4 a0 = make_float4(0.f, 0.f, 0.f, 0.f);
    float4 a1 = make_float4(0.f, 0.f, 0.f, 0.f);
    const bool tail = lane < 11;       // chunks 64..74 cover cols 256..299
    for (int e = beg; e < end; ++e) {
        const float* row = h + (size_t)colx[e] * C;
        float4 v = *(const float4*)&row[lane * 4];
        a0.x += v.x; a0.y += v.y; a0.z += v.z; a0.w += v.w;
        if (tail) {
            float4 u = *(const float4*)&row[(64 + lane) * 4];
            a1.x += u.x; a1.y += u.y; a1.z += u.z; a1.w += u.w;
        }
    }
    half4 vh, vl;
    {
        _Float16 hi, lo;
        split16(a0.x, hi, lo); vh[0] = hi; vl[0] = lo;
        split16(a0.y, hi, lo); vh[1] = hi; vl[1] = lo;
        split16(a0.z, hi, lo); vh[2] = hi; vl[2] = lo;
        split16(a0.w, hi, lo); vh[3] = hi; vl[3] = lo;
    }
    _Float16* oh = agh + (size_t)node * KP;
    _Float16* ol = agl + (size_t)node * KP;
    *(half4*)&oh[lane * 4] = vh;
    *(half4*)&ol[lane * 4] = vl;
    if (tail) {
        _Float16 hi, lo;
        split16(a1.x, hi, lo); vh[0] = hi; vl[0] = lo;
        split16(a1.y, hi, lo); vh[1] = hi; vl[1] = lo;
        split16(a1.z, hi, lo); vh[2] = hi; vl[2] = lo;
        split16(a1.w, hi, lo); vh[3] = hi; vl[3] = lo;
        *(half4*)&oh[(64 + lane) * 4] = vh;
        *(half4*)&ol[(64 + lane) * 4] = vl;
    }
}

// ---- fused MFMA GRU step, fp16 hi/lo split arithmetic (fp32-grade) ----
// gi = (agh + agl/S) @ (wch + wcl/S); gh = (hh + hl/S) @ (whh + whl/S)
// acc1 = hi*hi terms; acc2 = cross terms (scale S); dropped lo*lo ~ 2^-22.
__launch_bounds__(256)
__global__ void gru_f16(_Float16* __restrict__ hh, _Float16* __restrict__ hl,
                        const _Float16* __restrict__ agh, const _Float16* __restrict__ agl,
                        const _Float16* __restrict__ wch, const _Float16* __restrict__ wcl,
                        const _Float16* __restrict__ whh_, const _Float16* __restrict__ whl_,
                        const float* __restrict__ bih, const float* __restrict__ bhh,
                        float* __restrict__ h) {
    __shared__ _Float16 Lhh[32 * SP];
    __shared__ _Float16 Lhl[32 * SP];
    __shared__ _Float16 Lgh[32 * SP];
    const int tid = threadIdx.x;
    const int rowBase = blockIdx.x * 32;    // 625 * 32 = 20000 exact
    {
        int r = tid >> 3, c8 = tid & 7;
        const _Float16* ph = hh + (size_t)(rowBase + r) * KP;
        const _Float16* pl = hl + (size_t)(rowBase + r) * KP;
        const _Float16* pg = agh + (size_t)(rowBase + r) * KP;
        #pragma unroll
        for (int i = 0; i < 5; ++i) {
            int k = (c8 + i * 8) * 8;
            *(int4*)&Lhh[r * SP + k] = *(const int4*)&ph[k];
            *(int4*)&Lhl[r * SP + k] = *(const int4*)&pl[k];
            *(int4*)&Lgh[r * SP + k] = *(const int4*)&pg[k];
        }
    }
    __syncthreads();
    const int lane = tid & 63, w = tid >> 6;
    const int quad = lane >> 4, n15 = lane & 15;
    const _Float16* pgl0 = agl + (size_t)(rowBase + n15) * KP;
    const _Float16* pgl1 = agl + (size_t)(rowBase + 16 + n15) * KP;

    for (int ct = w; ct < 19; ct += 4) {
        floatx4 a1[2][6], a2[2][6];
        #pragma unroll
        for (int s = 0; s < 2; ++s)
            #pragma unroll
            for (int g = 0; g < 6; ++g) {
                a1[s][g] = (floatx4){0.f, 0.f, 0.f, 0.f};
                a2[s][g] = (floatx4){0.f, 0.f, 0.f, 0.f};
            }
        const int ncol = ct * 16 + n15;   // 0..303
        #pragma unroll
        for (int kt = 0; kt < 10; ++kt) {
            const int kc = kt * 4 + quad;
            const size_t bofs = ((size_t)kc * NPAD + ncol) * 8;
            half8 b0h = *(const half8*)&wch[bofs];
            half8 b1h = *(const half8*)&wch[GOFS + bofs];
            half8 b2h = *(const half8*)&wch[2 * GOFS + bofs];
            half8 b0l = *(const half8*)&wcl[bofs];
            half8 b1l = *(const half8*)&wcl[GOFS + bofs];
            half8 b2l = *(const half8*)&wcl[2 * GOFS + bofs];
            half8 b3h = *(const half8*)&whh_[bofs];
            half8 b4h = *(const half8*)&whh_[GOFS + bofs];
            half8 b5h = *(const half8*)&whh_[2 * GOFS + bofs];
            half8 b3l = *(const half8*)&whl_[bofs];
            half8 b4l = *(const half8*)&whl_[GOFS + bofs];
            half8 b5l = *(const half8*)&whl_[2 * GOFS + bofs];
            const int ko = kt * 32 + quad * 8;
            half8 GH[2], AH[2], AL[2], GL[2];
            GH[0] = *(const half8*)&Lgh[n15 * SP + ko];
            GH[1] = *(const half8*)&Lgh[(16 + n15) * SP + ko];
            AH[0] = *(const half8*)&Lhh[n15 * SP + ko];
            AH[1] = *(const half8*)&Lhh[(16 + n15) * SP + ko];
            AL[0] = *(const half8*)&Lhl[n15 * SP + ko];
            AL[1] = *(const half8*)&Lhl[(16 + n15) * SP + ko];
            GL[0] = *(const half8*)&pgl0[ko];
            GL[1] = *(const half8*)&pgl1[ko];
            #pragma unroll
            for (int s = 0; s < 2; ++s) {
                a1[s][0] = __builtin_amdgcn_mfma_f32_16x16x32_f16(GH[s], b0h, a1[s][0], 0, 0, 0);
                a2[s][0] = __builtin_amdgcn_mfma_f32_16x16x32_f16(GH[s], b0l, a2[s][0], 0, 0, 0);
                a2[s][0] = __builtin_amdgcn_mfma_f32_16x16x32_f16(GL[s], b0h, a2[s][0], 0, 0, 0);
                a1[s][1] = __builtin_amdgcn_mfma_f32_16x16x32_f16(GH[s], b1h, a1[s][1], 0, 0, 0);
                a2[s][1] = __builtin_amdgcn_mfma_f32_16x16x32_f16(GH[s], b1l, a2[s][1], 0, 0, 0);
                a2[s][1] = __builtin_amdgcn_mfma_f32_16x16x32_f16(GL[s], b1h, a2[s][1], 0, 0, 0);
                a1[s][2] = __builtin_amdgcn_mfma_f32_16x16x32_f16(GH[s], b2h, a1[s][2], 0, 0, 0);
                a2[s][2] = __builtin_amdgcn_mfma_f32_16x16x32_f16(GH[s], b2l, a2[s][2], 0, 0, 0);
                a2[s][2] = __builtin_amdgcn_mfma_f32_16x16x32_f16(GL[s], b2h, a2[s][2], 0, 0, 0);
                a1[s][3] = __builtin_amdgcn_mfma_f32_16x16x32_f16(AH[s], b3h, a1[s][3], 0, 0, 0);
                a2[s][3] = __builtin_amdgcn_mfma_f32_16x16x32_f16(AH[s], b3l, a2[s][3], 0, 0, 0);
                a2[s][3] = __builtin_amdgcn_mfma_f32_16x16x32_f16(AL[s], b3h, a2[s][3], 0, 0, 0);
                a1[s][4] = __builtin_amdgcn_mfma_f32_16x16x32_f16(AH[s], b4h, a1[s][4], 0, 0, 0);
                a2[s][4] = __builtin_amdgcn_mfma_f32_16x16x32_f16(AH[s], b4l, a2[s][4], 0, 0, 0);
                a2[s][4] = __builtin_amdgcn_mfma_f32_16x16x32_f16(AL[s], b4h, a2[s][4], 0, 0, 0);
                a1[s][5] = __builtin_amdgcn_mfma_f32_16x16x32_f16(AH[s], b5h, a1[s][5], 0, 0, 0);
                a2[s][5] = __builtin_amdgcn_mfma_f32_16x16x32_f16(AH[s], b5l, a2[s][5], 0, 0, 0);
                a2[s][5] = __builtin_amdgcn_mfma_f32_16x16x32_f16(AL[s], b5h, a2[s][5], 0, 0, 0);
            }
        }
        const int col = ncol;
        if (col < C) {
            const float invS = 1.0f / LOSCALE;
            float br = bih[col], bz = bih[C + col], bn = bih[2 * C + col];
            float cr = bhh[col], cz = bhh[C + col], cn = bhh[2 * C + col];
            #pragma unroll
            for (int s = 0; s < 2; ++s) {
                #pragma unroll
                for (int i = 0; i < 4; ++i) {
                    int grow = rowBase + s * 16 + quad * 4 + i;
                    float ir  = a1[s][0][i] + a2[s][0][i] * invS + br;
                    float iz  = a1[s][1][i] + a2[s][1][i] * invS + bz;
                    float inn = a1[s][2][i] + a2[s][2][i] * invS + bn;
                    float hr  = a1[s][3][i] + a2[s][3][i] * invS + cr;
                    float hz  = a1[s][4][i] + a2[s][4][i] * invS + cz;
                    float hn  = a1[s][5][i] + a2[s][5][i] * invS + cn;
                    float r = 1.f / (1.f + __expf(-(ir + hr)));
                    float z = 1.f / (1.f + __expf(-(iz + hz)));
                    float nn = tanhf(inn + r * hn);
                    float hold = h[(size_t)grow * C + col];
                    float hnew = (1.f - z) * nn + z * hold;
                    h[(size_t)grow * C + col] = hnew;
                    _Float16 nh, nl; split16(hnew, nh, nl);
                    hh[(size_t)grow * KP + col] = nh;
                    hl[(size_t)grow * KP + col] = nl;
                }
            }
        }
    }
}

// ---------------- relu (h fp32 + hh/hl fp16) ----------------
__global__ void relu_kernel(float* __restrict__ h, _Float16* __restrict__ hh,
                            _Float16* __restrict__ hl) {
    int idx = blockIdx.x * blockDim.x + threadIdx.x;
    if (idx >= N_NODES * C) return;
    int n = idx / C, c = idx - n * C;
    float v = fmaxf(h[idx], 0.f);
    h[idx] = v;
    _Float16 hi, lo; split16(v, hi, lo);
    hh[(size_t)n * KP + c] = hi;
    hl[(size_t)n * KP + c] = lo;
}

// ---------------- mean pool ----------------
__global__ void pool_kernel(const float* __restrict__ h, float* __restrict__ pooled) {
    int c = threadIdx.x;
    if (c >= C) return;
    float acc = 0.f;
    for (int n = blockIdx.x; n < N_NODES; n += gridDim.x)
        acc += h[(size_t)n * C + c];
    atomicAdd(&pooled[c], acc);
}

// ---------------- log_softmax ----------------
__global__ void lsm_kernel(const float* __restrict__ pooled, float* __restrict__ out) {
    __shared__ float sm[512];
    int t = threadIdx.x;
    float v = (t < C) ? pooled[t] * (1.0f / N_NODES) : -INFINITY;
    sm[t] = v;
    __syncthreads();
    for (int s = 256; s > 0; s >>= 1) {
        if (t < s) sm[t] = fmaxf(sm[t], sm[t + s]);
        __syncthreads();
    }
    float mx = sm[0];
    __syncthreads();
    float e = (t < C) ? expf(v - mx) : 0.f;
    sm[t] = e;
    __syncthreads();
    for (int s = 256; s > 0; s >>= 1) {
        if (t < s) sm[t] += sm[t + s];
        __syncthreads();
    }
    float lse = logf(sm[0]);
    if (t < C) out[t] = (v - mx) - lse;
}

extern "C" void kernel_launch(void* const* d_in, const int* in_sizes, int n_in,
                              void* d_out, int out_size, void* d_ws, size_t ws_size,
                              hipStream_t stream) {
    const float* x      = (const float*)d_in[0];
    const int*   ei     = (const int*)d_in[1];
    const int*   src    = ei;
    const int*   dst    = ei + N_EDGES;
    const float* W1     = (const float*)d_in[2];
    const float* g1_wih = (const float*)d_in[3];
    const float* g1_whh = (const float*)d_in[4];
    const float* g1_bih = (const float*)d_in[5];
    const float* g1_bhh = (const float*)d_in[6];
    const float* W2     = (const float*)d_in[7];
    const float* g2_wih = (const float*)d_in[8];
    const float* g2_whh = (const float*)d_in[9];
    const float* g2_bih = (const float*)d_in[10];
    const float* g2_bhh = (const float*)d_in[11];

    char* p = (char*)d_ws;
    float* h = (float*)p;               p += (size_t)N_NODES * C * 4;    // 24.0 MB
    _Float16* hh = (_Float16*)p;        p += (size_t)N_NODES * KP * 2;   // 12.8 MB
    _Float16* hl = (_Float16*)p;        p += (size_t)N_NODES * KP * 2;   // 12.8 MB
    _Float16* agh = (_Float16*)p;       p += (size_t)N_NODES * KP * 2;   // 12.8 MB
    _Float16* agl = (_Float16*)p;       p += (size_t)N_NODES * KP * 2;   // 12.8 MB
    _Float16* wch = (_Float16*)p;       p += (size_t)16 * WSTEP * 2;     //  9.34 MB
    _Float16* wcl = (_Float16*)p;       p += (size_t)16 * WSTEP * 2;     //  9.34 MB
    _Float16* wh_hi = (_Float16*)p;     p += (size_t)2 * WSTEP * 2;      //  1.17 MB
    _Float16* wh_lo = (_Float16*)p;     p += (size_t)2 * WSTEP * 2;      //  1.17 MB
    float* pooled = (float*)p;          p += 1216;
    int* row_ptr = (int*)p;             p += 80016;
    int* colx = (int*)p;                p += (size_t)N_EDGES * 4;        //  1.28 MB
    int* deg = (int*)p;                 p += 80000;
    int* cursor = (int*)p;              p += 80000;

    hipMemsetAsync(deg, 0, N_NODES * sizeof(int), stream);
    hipMemsetAsync(agh, 0, (size_t)N_NODES * KP * 2, stream);
    hipMemsetAsync(agl, 0, (size_t)N_NODES * KP * 2, stream);
    hipMemsetAsync(wch, 0, (size_t)16 * WSTEP * 2, stream);
    hipMemsetAsync(wcl, 0, (size_t)16 * WSTEP * 2, stream);
    hipMemsetAsync(wh_hi, 0, (size_t)2 * WSTEP * 2, stream);
    hipMemsetAsync(wh_lo, 0, (size_t)2 * WSTEP * 2, stream);
    hipMemsetAsync(pooled, 0, C * sizeof(float), stream);

    pad_kernel<<<(N_NODES * KP + 255) / 256, 256, 0, stream>>>(x, h, hh, hl);

    hist_kernel<<<(N_EDGES + 255) / 256, 256, 0, stream>>>(dst, deg);
    scan_kernel<<<1, 1024, 0, stream>>>(deg, row_ptr);
    cursor_copy<<<(N_NODES + 255) / 256, 256, 0, stream>>>(row_ptr, cursor);
    fill_kernel<<<(N_EDGES + 255) / 256, 256, 0, stream>>>(src, dst, cursor, colx);

    wcomb_split<<<dim3(15, 5, 16), 256, 0, stream>>>(W1, W2, g1_wih, g2_wih, wch, wcl);
    whh_split<<<(2 * 3 * C * C + 255) / 256, 256, 0, stream>>>(g1_whh, g2_whh, wh_hi, wh_lo);

    for (int layer = 0; layer < 2; ++layer) {
        const float* bih = layer ? g2_bih : g1_bih;
        const float* bhh = layer ? g2_bhh : g1_bhh;
        const _Float16* whh_hi = wh_hi + (size_t)layer * WSTEP;
        const _Float16* whh_lo = wh_lo + (size_t)layer * WSTEP;
        for (int step = 0; step < L_STEPS; ++step) {
            const _Float16* wc_hi = wch + (size_t)(layer * 8 + step) * WSTEP;
            const _Float16* wc_lo = wcl + (size_t)(layer * 8 + step) * WSTEP;
            aggregate_kernel<<<N_NODES / 4, 256, 0, stream>>>(h, row_ptr, colx, agh, agl);
            gru_f16<<<N_NODES / 32, 256, 0, stream>>>(
                hh, hl, agh, agl, wc_hi, wc_lo, whh_hi, whh_lo, bih, bhh, h);
        }
        if (layer == 0)
            relu_kernel<<<(N_NODES * C + 255) / 256, 256, 0, stream>>>(h, hh, hl);
    }

    pool_kernel<<<256, 320, 0, stream>>>(h, pooled);
    lsm_kernel<<<1, 512, 0, stream>>>(pooled, (float*)d_out);
}

// Round 7
// 5120.754 us; speedup vs baseline: 7.3705x; 2.1965x over previous
//
#include <hip/hip_runtime.h>
#include <math.h>

#define N_NODES 20000
#define N_EDGES 320000
#define F_IN 128
#define C 300
#define L_STEPS 8
#define KP 320                 // padded K (multiple of 32)
#define SP 328                 // LDS row stride (fp16 elems)
#define NPAD 304               // padded gate-col dim (19*16)
#define GOFS 97280             // 40*NPAD*8, per-gate block in swizzled weights
#define WSTEP 291840           // 3*GOFS, per (layer,step)
#define LOSCALE 2048.0f        // lo-part pre-scale (2^11), avoids fp16 denormals

typedef _Float16 half8 __attribute__((ext_vector_type(8)));
typedef _Float16 half4 __attribute__((ext_vector_type(4)));
typedef __attribute__((ext_vector_type(4))) float floatx4;

__device__ __forceinline__ void split16(float x, _Float16& hi, _Float16& lo) {
    hi = (_Float16)x;
    lo = (_Float16)((x - (float)hi) * LOSCALE);
}

// ---------------- pad x -> h (fp32) + hh/hl (fp16 split, stride KP) --------
__global__ void pad_kernel(const float* __restrict__ x, float* __restrict__ h,
                           _Float16* __restrict__ hh, _Float16* __restrict__ hl) {
    int idx = blockIdx.x * blockDim.x + threadIdx.x;
    if (idx >= N_NODES * KP) return;
    int n = idx / KP, c = idx - n * KP;
    float v = (c < F_IN) ? x[n * F_IN + c] : 0.0f;
    if (c < C) h[(size_t)n * C + c] = v;
    _Float16 hi, lo; split16(v, hi, lo);
    hh[idx] = hi; hl[idx] = lo;
}

// ---------------- CSR build (verified round 4) ----------------
__global__ void hist_kernel(const int* __restrict__ dst, int* __restrict__ deg) {
    int e = blockIdx.x * blockDim.x + threadIdx.x;
    if (e < N_EDGES) atomicAdd(&deg[dst[e]], 1);
}

__global__ void scan_kernel(const int* __restrict__ deg, int* __restrict__ row_ptr) {
    __shared__ int part[1024];
    const int PER = 20;
    int t = threadIdx.x;
    int base = t * PER;
    int vals[PER];
    int s = 0;
    #pragma unroll
    for (int i = 0; i < PER; ++i) {
        int idx = base + i;
        int v = (idx < N_NODES) ? deg[idx] : 0;
        vals[i] = s; s += v;
    }
    part[t] = s;
    __syncthreads();
    for (int off = 1; off < 1024; off <<= 1) {
        int v = (t >= off) ? part[t - off] : 0;
        __syncthreads();
        part[t] += v;
        __syncthreads();
    }
    int pre = (t == 0) ? 0 : part[t - 1];
    #pragma unroll
    for (int i = 0; i < PER; ++i) {
        int idx = base + i;
        if (idx < N_NODES) row_ptr[idx] = pre + vals[i];
    }
    if (t == 0) row_ptr[N_NODES] = N_EDGES;
}

__global__ void cursor_copy(const int* __restrict__ row_ptr, int* __restrict__ cur) {
    int i = blockIdx.x * blockDim.x + threadIdx.x;
    if (i < N_NODES) cur[i] = row_ptr[i];
}

__global__ void fill_kernel(const int* __restrict__ src, const int* __restrict__ dst,
                            int* __restrict__ cur, int* __restrict__ colx) {
    int e = blockIdx.x * blockDim.x + threadIdx.x;
    if (e >= N_EDGES) return;
    int d = dst[e];
    int p = atomicAdd(&cur[d], 1);
    colx[p] = src[e];
}

// ---- WcombT[r][gn] = sum_c W[r][c]*wih[gn][c]; swizzled fp16 hi/lo --------
__launch_bounds__(256)
__global__ void wcomb_split(const float* __restrict__ W1, const float* __restrict__ W2,
                            const float* __restrict__ wih1, const float* __restrict__ wih2,
                            _Float16* __restrict__ whi, _Float16* __restrict__ wlo) {
    int z = blockIdx.z, layer = z >> 3, step = z & 7;
    const float* A  = (layer ? W2 : W1) + (size_t)step * C * C;  // [r][c]
    const float* Bm = layer ? wih2 : wih1;                       // [gn][c]
    _Float16* ohi = whi + (size_t)z * WSTEP;
    _Float16* olo = wlo + (size_t)z * WSTEP;
    __shared__ float As[16][68];
    __shared__ float Bs[16][68];
    int tid = threadIdx.x;
    int tx = tid & 15, ty = tid >> 4;
    int rowBase = blockIdx.y * 64, colBase = blockIdx.x * 64;
    float acc[4][4] = {};
    int lr = tid >> 2, k4 = (tid & 3) * 4;
    for (int k0 = 0; k0 < C; k0 += 16) {
        {
            int gr = rowBase + lr;
            int gn = colBase + lr;
            #pragma unroll
            for (int j = 0; j < 4; ++j) {
                int k = k0 + k4 + j;
                As[k4 + j][lr] = (gr < C && k < C) ? A[(size_t)gr * C + k] : 0.f;
                Bs[k4 + j][lr] = (gn < 3 * C && k < C) ? Bm[(size_t)gn * C + k] : 0.f;
            }
        }
        __syncthreads();
        #pragma unroll
        for (int k = 0; k < 16; ++k) {
            float4 a = *(const float4*)&As[k][ty * 4];
            float4 b = *(const float4*)&Bs[k][tx * 4];
            float av[4] = {a.x, a.y, a.z, a.w};
            float bv[4] = {b.x, b.y, b.z, b.w};
            #pragma unroll
            for (int i = 0; i < 4; ++i)
                #pragma unroll
                for (int j = 0; j < 4; ++j)
                    acc[i][j] += av[i] * bv[j];
        }
        __syncthreads();
    }
    #pragma unroll
    for (int i = 0; i < 4; ++i) {
        int r = rowBase + ty * 4 + i;
        if (r >= C) continue;
        #pragma unroll
        for (int j = 0; j < 4; ++j) {
            int gn = colBase + tx * 4 + j;
            if (gn >= 3 * C) continue;
            int g = (gn >= 2 * C) ? 2 : ((gn >= C) ? 1 : 0);
            int n = gn - g * C;
            size_t idx = (((size_t)g * 40 + (r >> 3)) * NPAD + n) * 8 + (r & 7);
            _Float16 hi, lo; split16(acc[i][j], hi, lo);
            ohi[idx] = hi; olo[idx] = lo;
        }
    }
}

// ---- whh^T swizzle + split: B[k][gn] = whh[gn][k], fp16 hi/lo ----
__global__ void whh_split(const float* __restrict__ whh1, const float* __restrict__ whh2,
                          _Float16* __restrict__ whi, _Float16* __restrict__ wlo) {
    int idx = blockIdx.x * blockDim.x + threadIdx.x;
    if (idx >= 2 * 3 * C * C) return;
    int k = idx % C;
    int rest = idx / C;
    int gn = rest % (3 * C);
    int layer = rest / (3 * C);
    int g = (gn >= 2 * C) ? 2 : ((gn >= C) ? 1 : 0);
    int n = gn - g * C;
    float v = (layer ? whh2 : whh1)[(size_t)gn * C + k];
    size_t o = (size_t)layer * WSTEP + (((size_t)g * 40 + (k >> 3)) * NPAD + n) * 8 + (k & 7);
    _Float16 hi, lo; split16(v, hi, lo);
    whi[o] = hi; wlo[o] = lo;
}

// ---- CSR gather from fp32 h -> exact fp16 hi/lo split agg [N x KP] ----
__global__ void aggregate_kernel(const float* __restrict__ h,
                                 const int* __restrict__ rowp,
                                 const int* __restrict__ colx,
                                 _Float16* __restrict__ agh, _Float16* __restrict__ agl) {
    const int node = blockIdx.x * 4 + (threadIdx.x >> 6);
    const int lane = threadIdx.x & 63;
    const int beg = rowp[node], end = rowp[node + 1];
    float4 a0 = make_float4(0.f, 0.f, 0.f, 0.f);
    float4 a1 = make_float4(0.f, 0.f, 0.f, 0.f);
    const bool tail = lane < 11;       // chunks 64..74 cover cols 256..299
    for (int e = beg; e < end; ++e) {
        const float* row = h + (size_t)colx[e] * C;
        float4 v = *(const float4*)&row[lane * 4];
        a0.x += v.x; a0.y += v.y; a0.z += v.z; a0.w += v.w;
        if (tail) {
            float4 u = *(const float4*)&row[(64 + lane) * 4];
            a1.x += u.x; a1.y += u.y; a1.z += u.z; a1.w += u.w;
        }
    }
    half4 vh, vl;
    {
        _Float16 hi, lo;
        split16(a0.x, hi, lo); vh[0] = hi; vl[0] = lo;
        split16(a0.y, hi, lo); vh[1] = hi; vl[1] = lo;
        split16(a0.z, hi, lo); vh[2] = hi; vl[2] = lo;
        split16(a0.w, hi, lo); vh[3] = hi; vl[3] = lo;
    }
    _Float16* oh = agh + (size_t)node * KP;
    _Float16* ol = agl + (size_t)node * KP;
    *(half4*)&oh[lane * 4] = vh;
    *(half4*)&ol[lane * 4] = vl;
    if (tail) {
        _Float16 hi, lo;
        split16(a1.x, hi, lo); vh[0] = hi; vl[0] = lo;
        split16(a1.y, hi, lo); vh[1] = hi; vl[1] = lo;
        split16(a1.z, hi, lo); vh[2] = hi; vl[2] = lo;
        split16(a1.w, hi, lo); vh[3] = hi; vl[3] = lo;
        *(half4*)&oh[(64 + lane) * 4] = vh;
        *(half4*)&ol[(64 + lane) * 4] = vl;
    }
}

// ---- B-fragment bundle (12 matrices: {wc,wh} x {r,z,n} x {hi,lo}) ----
struct BFrag { half8 v[12]; };
__device__ __forceinline__ BFrag load_bfrags(const _Float16* __restrict__ wch,
                                             const _Float16* __restrict__ wcl,
                                             const _Float16* __restrict__ whh_,
                                             const _Float16* __restrict__ whl_,
                                             int kc, int ncol) {
    BFrag f;
    const size_t bofs = ((size_t)kc * NPAD + ncol) * 8;
    f.v[0]  = *(const half8*)&wch[bofs];
    f.v[1]  = *(const half8*)&wch[GOFS + bofs];
    f.v[2]  = *(const half8*)&wch[2 * GOFS + bofs];
    f.v[3]  = *(const half8*)&wcl[bofs];
    f.v[4]  = *(const half8*)&wcl[GOFS + bofs];
    f.v[5]  = *(const half8*)&wcl[2 * GOFS + bofs];
    f.v[6]  = *(const half8*)&whh_[bofs];
    f.v[7]  = *(const half8*)&whh_[GOFS + bofs];
    f.v[8]  = *(const half8*)&whh_[2 * GOFS + bofs];
    f.v[9]  = *(const half8*)&whl_[bofs];
    f.v[10] = *(const half8*)&whl_[GOFS + bofs];
    f.v[11] = *(const half8*)&whl_[2 * GOFS + bofs];
    return f;
}

// ---- fused MFMA GRU step, fp16 hi/lo split arithmetic ----
// Wave mapping: w -> (s = w>>1 row-subtile of 16, parity = w&1 ct-stride-2).
// acc = 12 floatx4 (48 VGPR) per wave; explicit B double-buffer.
__launch_bounds__(256, 2)
__global__ void gru_f16(_Float16* __restrict__ hh, _Float16* __restrict__ hl,
                        const _Float16* __restrict__ agh, const _Float16* __restrict__ agl,
                        const _Float16* __restrict__ wch, const _Float16* __restrict__ wcl,
                        const _Float16* __restrict__ whh_, const _Float16* __restrict__ whl_,
                        const float* __restrict__ bih, const float* __restrict__ bhh,
                        float* __restrict__ h) {
    __shared__ _Float16 Lhh[32 * SP];
    __shared__ _Float16 Lhl[32 * SP];
    __shared__ _Float16 Lgh[32 * SP];
    const int tid = threadIdx.x;
    const int rowBase = blockIdx.x * 32;    // 625 * 32 = 20000 exact
    {
        int r = tid >> 3, c8 = tid & 7;
        const _Float16* ph = hh + (size_t)(rowBase + r) * KP;
        const _Float16* pl = hl + (size_t)(rowBase + r) * KP;
        const _Float16* pg = agh + (size_t)(rowBase + r) * KP;
        #pragma unroll
        for (int i = 0; i < 5; ++i) {
            int k = (c8 + i * 8) * 8;
            *(int4*)&Lhh[r * SP + k] = *(const int4*)&ph[k];
            *(int4*)&Lhl[r * SP + k] = *(const int4*)&pl[k];
            *(int4*)&Lgh[r * SP + k] = *(const int4*)&pg[k];
        }
    }
    __syncthreads();
    const int lane = tid & 63, w = tid >> 6;
    const int quad = lane >> 4, n15 = lane & 15;
    const int s = w >> 1;          // row-subtile (0 or 1)
    const int parity = w & 1;      // ct parity
    const int arow = s * 16 + n15; // A-fragment row within block
    const _Float16* pgl = agl + (size_t)(rowBase + arow) * KP;

    for (int ct = parity; ct < 19; ct += 2) {
        floatx4 a1[6], a2[6];
        #pragma unroll
        for (int g = 0; g < 6; ++g) {
            a1[g] = (floatx4){0.f, 0.f, 0.f, 0.f};
            a2[g] = (floatx4){0.f, 0.f, 0.f, 0.f};
        }
        const int ncol = ct * 16 + n15;   // 0..303
        BFrag B0 = load_bfrags(wch, wcl, whh_, whl_, 0 * 4 + quad, ncol);
        BFrag B1;
        #pragma unroll
        for (int kt = 0; kt < 10; ++kt) {
            if (kt < 9) {
                if (kt & 1) B0 = load_bfrags(wch, wcl, whh_, whl_, (kt + 1) * 4 + quad, ncol);
                else        B1 = load_bfrags(wch, wcl, whh_, whl_, (kt + 1) * 4 + quad, ncol);
            }
            const BFrag& B = (kt & 1) ? B1 : B0;
            const int ko = kt * 32 + quad * 8;
            half8 GH = *(const half8*)&Lgh[arow * SP + ko];
            half8 AH = *(const half8*)&Lhh[arow * SP + ko];
            half8 AL = *(const half8*)&Lhl[arow * SP + ko];
            half8 GL = *(const half8*)&pgl[ko];
            a1[0] = __builtin_amdgcn_mfma_f32_16x16x32_f16(GH, B.v[0], a1[0], 0, 0, 0);
            a2[0] = __builtin_amdgcn_mfma_f32_16x16x32_f16(GH, B.v[3], a2[0], 0, 0, 0);
            a2[0] = __builtin_amdgcn_mfma_f32_16x16x32_f16(GL, B.v[0], a2[0], 0, 0, 0);
            a1[1] = __builtin_amdgcn_mfma_f32_16x16x32_f16(GH, B.v[1], a1[1], 0, 0, 0);
            a2[1] = __builtin_amdgcn_mfma_f32_16x16x32_f16(GH, B.v[4], a2[1], 0, 0, 0);
            a2[1] = __builtin_amdgcn_mfma_f32_16x16x32_f16(GL, B.v[1], a2[1], 0, 0, 0);
            a1[2] = __builtin_amdgcn_mfma_f32_16x16x32_f16(GH, B.v[2], a1[2], 0, 0, 0);
            a2[2] = __builtin_amdgcn_mfma_f32_16x16x32_f16(GH, B.v[5], a2[2], 0, 0, 0);
            a2[2] = __builtin_amdgcn_mfma_f32_16x16x32_f16(GL, B.v[2], a2[2], 0, 0, 0);
            a1[3] = __builtin_amdgcn_mfma_f32_16x16x32_f16(AH, B.v[6], a1[3], 0, 0, 0);
            a2[3] = __builtin_amdgcn_mfma_f32_16x16x32_f16(AH, B.v[9], a2[3], 0, 0, 0);
            a2[3] = __builtin_amdgcn_mfma_f32_16x16x32_f16(AL, B.v[6], a2[3], 0, 0, 0);
            a1[4] = __builtin_amdgcn_mfma_f32_16x16x32_f16(AH, B.v[7], a1[4], 0, 0, 0);
            a2[4] = __builtin_amdgcn_mfma_f32_16x16x32_f16(AH, B.v[10], a2[4], 0, 0, 0);
            a2[4] = __builtin_amdgcn_mfma_f32_16x16x32_f16(AL, B.v[7], a2[4], 0, 0, 0);
            a1[5] = __builtin_amdgcn_mfma_f32_16x16x32_f16(AH, B.v[8], a1[5], 0, 0, 0);
            a2[5] = __builtin_amdgcn_mfma_f32_16x16x32_f16(AH, B.v[11], a2[5], 0, 0, 0);
            a2[5] = __builtin_amdgcn_mfma_f32_16x16x32_f16(AL, B.v[8], a2[5], 0, 0, 0);
        }
        const int col = ncol;
        if (col < C) {
            const float invS = 1.0f / LOSCALE;
            float br = bih[col], bz = bih[C + col], bn = bih[2 * C + col];
            float cr = bhh[col], cz = bhh[C + col], cn = bhh[2 * C + col];
            #pragma unroll
            for (int i = 0; i < 4; ++i) {
                int grow = rowBase + s * 16 + quad * 4 + i;
                float ir  = a1[0][i] + a2[0][i] * invS + br;
                float iz  = a1[1][i] + a2[1][i] * invS + bz;
                float inn = a1[2][i] + a2[2][i] * invS + bn;
                float hr  = a1[3][i] + a2[3][i] * invS + cr;
                float hz  = a1[4][i] + a2[4][i] * invS + cz;
                float hn  = a1[5][i] + a2[5][i] * invS + cn;
                float r = 1.f / (1.f + __expf(-(ir + hr)));
                float z = 1.f / (1.f + __expf(-(iz + hz)));
                float nn = tanhf(inn + r * hn);
                float hold = h[(size_t)grow * C + col];
                float hnew = (1.f - z) * nn + z * hold;
                h[(size_t)grow * C + col] = hnew;
                _Float16 nh, nl; split16(hnew, nh, nl);
                hh[(size_t)grow * KP + col] = nh;
                hl[(size_t)grow * KP + col] = nl;
            }
        }
    }
}

// ---------------- relu (h fp32 + hh/hl fp16) ----------------
__global__ void relu_kernel(float* __restrict__ h, _Float16* __restrict__ hh,
                            _Float16* __restrict__ hl) {
    int idx = blockIdx.x * blockDim.x + threadIdx.x;
    if (idx >= N_NODES * C) return;
    int n = idx / C, c = idx - n * C;
    float v = fmaxf(h[idx], 0.f);
    h[idx] = v;
    _Float16 hi, lo; split16(v, hi, lo);
    hh[(size_t)n * KP + c] = hi;
    hl[(size_t)n * KP + c] = lo;
}

// ---------------- mean pool ----------------
__global__ void pool_kernel(const float* __restrict__ h, float* __restrict__ pooled) {
    int c = threadIdx.x;
    if (c >= C) return;
    float acc = 0.f;
    for (int n = blockIdx.x; n < N_NODES; n += gridDim.x)
        acc += h[(size_t)n * C + c];
    atomicAdd(&pooled[c], acc);
}

// ---------------- log_softmax ----------------
__global__ void lsm_kernel(const float* __restrict__ pooled, float* __restrict__ out) {
    __shared__ float sm[512];
    int t = threadIdx.x;
    float v = (t < C) ? pooled[t] * (1.0f / N_NODES) : -INFINITY;
    sm[t] = v;
    __syncthreads();
    for (int s = 256; s > 0; s >>= 1) {
        if (t < s) sm[t] = fmaxf(sm[t], sm[t + s]);
        __syncthreads();
    }
    float mx = sm[0];
    __syncthreads();
    float e = (t < C) ? expf(v - mx) : 0.f;
    sm[t] = e;
    __syncthreads();
    for (int s = 256; s > 0; s >>= 1) {
        if (t < s) sm[t] += sm[t + s];
        __syncthreads();
    }
    float lse = logf(sm[0]);
    if (t < C) out[t] = (v - mx) - lse;
}

extern "C" void kernel_launch(void* const* d_in, const int* in_sizes, int n_in,
                              void* d_out, int out_size, void* d_ws, size_t ws_size,
                              hipStream_t stream) {
    const float* x      = (const float*)d_in[0];
    const int*   ei     = (const int*)d_in[1];
    const int*   src    = ei;
    const int*   dst    = ei + N_EDGES;
    const float* W1     = (const float*)d_in[2];
    const float* g1_wih = (const float*)d_in[3];
    const float* g1_whh = (const float*)d_in[4];
    const float* g1_bih = (const float*)d_in[5];
    const float* g1_bhh = (const float*)d_in[6];
    const float* W2     = (const float*)d_in[7];
    const float* g2_wih = (const float*)d_in[8];
    const float* g2_whh = (const float*)d_in[9];
    const float* g2_bih = (const float*)d_in[10];
    const float* g2_bhh = (const float*)d_in[11];

    char* p = (char*)d_ws;
    float* h = (float*)p;               p += (size_t)N_NODES * C * 4;    // 24.0 MB
    _Float16* hh = (_Float16*)p;        p += (size_t)N_NODES * KP * 2;   // 12.8 MB
    _Float16* hl = (_Float16*)p;        p += (size_t)N_NODES * KP * 2;   // 12.8 MB
    _Float16* agh = (_Float16*)p;       p += (size_t)N_NODES * KP * 2;   // 12.8 MB
    _Float16* agl = (_Float16*)p;       p += (size_t)N_NODES * KP * 2;   // 12.8 MB
    _Float16* wch = (_Float16*)p;       p += (size_t)16 * WSTEP * 2;     //  9.34 MB
    _Float16* wcl = (_Float16*)p;       p += (size_t)16 * WSTEP * 2;     //  9.34 MB
    _Float16* wh_hi = (_Float16*)p;     p += (size_t)2 * WSTEP * 2;      //  1.17 MB
    _Float16* wh_lo = (_Float16*)p;     p += (size_t)2 * WSTEP * 2;      //  1.17 MB
    float* pooled = (float*)p;          p += 1216;
    int* row_ptr = (int*)p;             p += 80016;
    int* colx = (int*)p;                p += (size_t)N_EDGES * 4;        //  1.28 MB
    int* deg = (int*)p;                 p += 80000;
    int* cursor = (int*)p;              p += 80000;

    hipMemsetAsync(deg, 0, N_NODES * sizeof(int), stream);
    hipMemsetAsync(agh, 0, (size_t)N_NODES * KP * 2, stream);
    hipMemsetAsync(agl, 0, (size_t)N_NODES * KP * 2, stream);
    hipMemsetAsync(wch, 0, (size_t)16 * WSTEP * 2, stream);
    hipMemsetAsync(wcl, 0, (size_t)16 * WSTEP * 2, stream);
    hipMemsetAsync(wh_hi, 0, (size_t)2 * WSTEP * 2, stream);
    hipMemsetAsync(wh_lo, 0, (size_t)2 * WSTEP * 2, stream);
    hipMemsetAsync(pooled, 0, C * sizeof(float), stream);

    pad_kernel<<<(N_NODES * KP + 255) / 256, 256, 0, stream>>>(x, h, hh, hl);

    hist_kernel<<<(N_EDGES + 255) / 256, 256, 0, stream>>>(dst, deg);
    scan_kernel<<<1, 1024, 0, stream>>>(deg, row_ptr);
    cursor_copy<<<(N_NODES + 255) / 256, 256, 0, stream>>>(row_ptr, cursor);
    fill_kernel<<<(N_EDGES + 255) / 256, 256, 0, stream>>>(src, dst, cursor, colx);

    wcomb_split<<<dim3(15, 5, 16), 256, 0, stream>>>(W1, W2, g1_wih, g2_wih, wch, wcl);
    whh_split<<<(2 * 3 * C * C + 255) / 256, 256, 0, stream>>>(g1_whh, g2_whh, wh_hi, wh_lo);

    for (int layer = 0; layer < 2; ++layer) {
        const float* bih = layer ? g2_bih : g1_bih;
        const float* bhh = layer ? g2_bhh : g1_bhh;
        const _Float16* whh_hi = wh_hi + (size_t)layer * WSTEP;
        const _Float16* whh_lo = wh_lo + (size_t)layer * WSTEP;
        for (int step = 0; step < L_STEPS; ++step) {
            const _Float16* wc_hi = wch + (size_t)(layer * 8 + step) * WSTEP;
            const _Float16* wc_lo = wcl + (size_t)(layer * 8 + step) * WSTEP;
            aggregate_kernel<<<N_NODES / 4, 256, 0, stream>>>(h, row_ptr, colx, agh, agl);
            gru_f16<<<N_NODES / 32, 256, 0, stream>>>(
                hh, hl, agh, agl, wc_hi, wc_lo, whh_hi, whh_lo, bih, bhh, h);
        }
        if (layer == 0)
            relu_kernel<<<(N_NODES * C + 255) / 256, 256, 0, stream>>>(h, hh, hl);
    }

    pool_kernel<<<256, 320, 0, stream>>>(h, pooled);
    lsm_kernel<<<1, 512, 0, stream>>>(pooled, (float*)d_out);
}